// Round 1
// baseline (245.336 us; speedup 1.0000x reference)
//
#include <hip/hip_runtime.h>
#include <stdint.h>

typedef short s16x8 __attribute__((ext_vector_type(8)));
typedef float f32x4 __attribute__((ext_vector_type(4)));

union FragU { uint4 u; s16x8 v; };

static __device__ __forceinline__ unsigned short f2bf(float f) {
  union { float f; uint32_t u; } x; x.f = f;
  uint32_t r = x.u + 0x7FFFu + ((x.u >> 16) & 1u);  // RNE
  return (unsigned short)(r >> 16);
}

// ---------------- weight transpose: fp32 W[k][n] -> bf16 WT[n][k] ----------------
__global__ __launch_bounds__(256) void wt_kernel(const float* __restrict__ W,
                                                 unsigned short* __restrict__ WT) {
  __shared__ unsigned short tile[64][68];
  const int t = threadIdx.x;
  const int n0 = blockIdx.x * 64, k0 = blockIdx.y * 64;
  const int r = t >> 4, c4 = (t & 15) * 4;
#pragma unroll
  for (int i = 0; i < 4; ++i) {
    const int k = i * 16 + r;
    const float4 v = *(const float4*)&W[(k0 + k) * 1024 + n0 + c4];
    tile[k][c4 + 0] = f2bf(v.x);
    tile[k][c4 + 1] = f2bf(v.y);
    tile[k][c4 + 2] = f2bf(v.z);
    tile[k][c4 + 3] = f2bf(v.w);
  }
  __syncthreads();
#pragma unroll
  for (int i = 0; i < 4; ++i) {
    const int n = i * 16 + r;
    ushort4 o;
    o.x = tile[c4 + 0][n];
    o.y = tile[c4 + 1][n];
    o.z = tile[c4 + 2][n];
    o.w = tile[c4 + 3][n];
    *(ushort4*)&WT[(n0 + n) * 1024 + k0 + c4] = o;
  }
}

// ---------------- GEMM: C[M][N] = A[M][K] * BT[N][K]^T, epilogue (acc+bias)*scale
// AMODE: 0 = A fp32, 1 = A bf16.  OMODE: 0 = bf16 [M][N], 1 = bf16 Vt layout, 2 = fp32 [M][N]
// Tile: BM=128, BN=64, BK=32. 4 waves, each 32(m) x 64(n). LDS pitch 40 bf16 (80B, 2-way banks).
template <int AMODE, int OMODE>
__global__ __launch_bounds__(256) void gemm_kernel(const void* __restrict__ Aptr,
                                                   const unsigned short* __restrict__ BT,
                                                   const float* __restrict__ bias,
                                                   void* __restrict__ Out,
                                                   const int M, const int N, const int K,
                                                   const float scale) {
  constexpr int P = 40;
  __shared__ unsigned short As[128 * P];
  __shared__ unsigned short Bs[64 * P];
  const int t = threadIdx.x;
  const int lane = t & 63, w = t >> 6;
  const int g = lane >> 4, li = lane & 15;
  const int m0 = blockIdx.y * 128, n0 = blockIdx.x * 64;

  f32x4 acc[2][4] = {};

  for (int k0 = 0; k0 < K; k0 += 32) {
    __syncthreads();
    // stage A: 128 rows x 4 chunks of 16B (8 bf16)
#pragma unroll
    for (int i = 0; i < 2; ++i) {
      const int chunk = t + 256 * i;
      const int row = chunk >> 2, ch = chunk & 3;
      uint4 val;
      if constexpr (AMODE == 0) {
        const float* ga = (const float*)Aptr + (m0 + row) * K + k0 + ch * 8;
        const float4 f0 = *(const float4*)ga;
        const float4 f1 = *(const float4*)(ga + 4);
        val.x = (uint32_t)f2bf(f0.x) | ((uint32_t)f2bf(f0.y) << 16);
        val.y = (uint32_t)f2bf(f0.z) | ((uint32_t)f2bf(f0.w) << 16);
        val.z = (uint32_t)f2bf(f1.x) | ((uint32_t)f2bf(f1.y) << 16);
        val.w = (uint32_t)f2bf(f1.z) | ((uint32_t)f2bf(f1.w) << 16);
      } else {
        val = *(const uint4*)((const unsigned short*)Aptr + (m0 + row) * K + k0 + ch * 8);
      }
      *(uint4*)&As[row * P + ch * 8] = val;
    }
    // stage BT: 64 rows x 4 chunks
    {
      const int row = t >> 2, ch = t & 3;
      *(uint4*)&Bs[row * P + ch * 8] = *(const uint4*)(BT + (n0 + row) * K + k0 + ch * 8);
    }
    __syncthreads();

    FragU a[2], bfr[4];
#pragma unroll
    for (int fm = 0; fm < 2; ++fm)
      a[fm].u = *(const uint4*)&As[(w * 32 + fm * 16 + li) * P + g * 8];
#pragma unroll
    for (int fn = 0; fn < 4; ++fn)
      bfr[fn].u = *(const uint4*)&Bs[(fn * 16 + li) * P + g * 8];
#pragma unroll
    for (int fm = 0; fm < 2; ++fm)
#pragma unroll
      for (int fn = 0; fn < 4; ++fn)
        acc[fm][fn] = __builtin_amdgcn_mfma_f32_16x16x32_bf16(a[fm].v, bfr[fn].v, acc[fm][fn], 0, 0, 0);
  }

#pragma unroll
  for (int fn = 0; fn < 4; ++fn) {
    const int n = n0 + fn * 16 + li;
    const float bv = bias[n];
#pragma unroll
    for (int fm = 0; fm < 2; ++fm) {
      const int mb = m0 + w * 32 + fm * 16 + g * 4;  // 4 consecutive m: mb..mb+3
      const f32x4 v = acc[fm][fn];
      if constexpr (OMODE == 0) {
        unsigned short* o = (unsigned short*)Out;
#pragma unroll
        for (int r = 0; r < 4; ++r) o[(mb + r) * N + n] = f2bf((v[r] + bv) * scale);
      } else if constexpr (OMODE == 1) {
        // Vt[(b*1024 + n) * 2048 + s], b = m>>11, s = m&2047
        unsigned short* o = (unsigned short*)Out;
        const int bb = mb >> 11, s = mb & 2047;
        ushort4 pk;
        pk.x = f2bf((v[0] + bv) * scale);
        pk.y = f2bf((v[1] + bv) * scale);
        pk.z = f2bf((v[2] + bv) * scale);
        pk.w = f2bf((v[3] + bv) * scale);
        *(ushort4*)&o[(bb * 1024 + n) * 2048 + s] = pk;
      } else {
        float* o = (float*)Out;
#pragma unroll
        for (int r = 0; r < 4; ++r) o[(mb + r) * N + n] = (v[r] + bv) * scale;
      }
    }
  }
}

// ---------------- flash attention ----------------
// Q,K bf16 [B*S][1024] (Q pre-scaled by 1/8); Vt bf16 [(b*1024 + h*64 + d)][2048]
// grid: (S/64, B*H), block 256 (4 waves). Swapped QK^T: S^T = mfma(Kfrag, Qfrag) -> q in lane&15.
__global__ __launch_bounds__(256) void attn_kernel(const unsigned short* __restrict__ Qb,
                                                   const unsigned short* __restrict__ Kb,
                                                   const unsigned short* __restrict__ Vt,
                                                   const int* __restrict__ mask,
                                                   unsigned short* __restrict__ ctx) {
  constexpr int AP = 88;  // LDS pitch in bf16 (176B): 2-way bank aliasing only
  __shared__ unsigned short Qs[64 * AP];
  __shared__ unsigned short Ks[64 * AP];
  __shared__ unsigned short Vs[64 * AP];
  __shared__ unsigned short Ps[4][16 * AP];
  __shared__ int msk[64];
  const int t = threadIdx.x, lane = t & 63, w = t >> 6;
  const int g = lane >> 4, li = lane & 15;
  const int bh = blockIdx.y, b = bh >> 4, h = bh & 15;
  const int q0 = blockIdx.x * 64;

  // stage Q tile [64 q][64 d]
  {
    const int row = t >> 2, cb = t & 3;
    const unsigned short* src = Qb + (b * 2048 + q0 + row) * 1024 + h * 64;
    *(uint4*)&Qs[row * AP + cb * 8] = *(const uint4*)(src + cb * 8);
    *(uint4*)&Qs[row * AP + (cb + 4) * 8] = *(const uint4*)(src + (cb + 4) * 8);
  }

  f32x4 acc_o[4] = {};
  float m_run = -1e30f, l_run = 0.f;

  for (int kv0 = 0; kv0 < 2048; kv0 += 64) {
    __syncthreads();
    {
      const int row = t >> 2, cb = t & 3;
      const unsigned short* ks = Kb + (b * 2048 + kv0 + row) * 1024 + h * 64;
      *(uint4*)&Ks[row * AP + cb * 8] = *(const uint4*)(ks + cb * 8);
      *(uint4*)&Ks[row * AP + (cb + 4) * 8] = *(const uint4*)(ks + (cb + 4) * 8);
      const unsigned short* vs = Vt + (b * 1024 + h * 64 + row) * 2048 + kv0;
      *(uint4*)&Vs[row * AP + cb * 8] = *(const uint4*)(vs + cb * 8);
      *(uint4*)&Vs[row * AP + (cb + 4) * 8] = *(const uint4*)(vs + (cb + 4) * 8);
      if (t < 64) msk[t] = mask[b * 2048 + kv0 + t];
    }
    __syncthreads();

    // QK^T (swapped): sc[fs] = S^T[fs*16 + g*4 + r][w*16 + li]
    f32x4 sc[4] = {};
#pragma unroll
    for (int kc = 0; kc < 2; ++kc) {
      FragU qf;
      qf.u = *(const uint4*)&Qs[(w * 16 + li) * AP + kc * 32 + g * 8];
#pragma unroll
      for (int fs = 0; fs < 4; ++fs) {
        FragU kf;
        kf.u = *(const uint4*)&Ks[(fs * 16 + li) * AP + kc * 32 + g * 8];
        sc[fs] = __builtin_amdgcn_mfma_f32_16x16x32_bf16(kf.v, qf.v, sc[fs], 0, 0, 0);
      }
    }

    // mask + online softmax (per q = lane&15; s_k spread over g and regs)
    float p[16];
    float pm = -1e30f;
#pragma unroll
    for (int fs = 0; fs < 4; ++fs)
#pragma unroll
      for (int r = 0; r < 4; ++r) {
        const float s = sc[fs][r] + (msk[fs * 16 + g * 4 + r] ? 0.f : -1e30f);
        p[fs * 4 + r] = s;
        pm = fmaxf(pm, s);
      }
    pm = fmaxf(pm, __shfl_xor(pm, 16, 64));
    pm = fmaxf(pm, __shfl_xor(pm, 32, 64));
    const float m_new = fmaxf(m_run, pm);
    const float rescale = __expf(m_run - m_new);
    float rsum = 0.f;
#pragma unroll
    for (int i = 0; i < 16; ++i) {
      p[i] = __expf(p[i] - m_new);
      rsum += p[i];
    }
    rsum += __shfl_xor(rsum, 16, 64);
    rsum += __shfl_xor(rsum, 32, 64);
    l_run = l_run * rescale + rsum;
    m_run = m_new;
#pragma unroll
    for (int fd = 0; fd < 4; ++fd) acc_o[fd] *= rescale;

    // write P[q][s_k] bf16 to per-wave LDS (pairs -> u32)
    unsigned short* pw = &Ps[w][0];
#pragma unroll
    for (int fs = 0; fs < 4; ++fs)
#pragma unroll
      for (int h2 = 0; h2 < 2; ++h2) {
        const uint32_t u = (uint32_t)f2bf(p[fs * 4 + 2 * h2]) |
                           ((uint32_t)f2bf(p[fs * 4 + 2 * h2 + 1]) << 16);
        *(uint32_t*)&pw[li * AP + fs * 16 + g * 4 + 2 * h2] = u;
      }
    __asm__ volatile("s_waitcnt lgkmcnt(0)" ::: "memory");

    // PV: ctx^T[d][q] += V^T P  (A = Vt frag, B = P frag)
#pragma unroll
    for (int kc = 0; kc < 2; ++kc) {
      FragU pf;
      pf.u = *(const uint4*)&pw[li * AP + kc * 32 + g * 8];
#pragma unroll
      for (int fd = 0; fd < 4; ++fd) {
        FragU vf;
        vf.u = *(const uint4*)&Vs[(fd * 16 + li) * AP + kc * 32 + g * 8];
        acc_o[fd] = __builtin_amdgcn_mfma_f32_16x16x32_bf16(vf.v, pf.v, acc_o[fd], 0, 0, 0);
      }
    }
  }

  // epilogue: ctx[(b*2048 + q0 + q)][h*64 + d] = acc/l
  const float inv_l = 1.0f / l_run;
  const int qg = b * 2048 + q0 + w * 16 + li;
#pragma unroll
  for (int fd = 0; fd < 4; ++fd) {
    ushort4 pk;
    pk.x = f2bf(acc_o[fd][0] * inv_l);
    pk.y = f2bf(acc_o[fd][1] * inv_l);
    pk.z = f2bf(acc_o[fd][2] * inv_l);
    pk.w = f2bf(acc_o[fd][3] * inv_l);
    *(ushort4*)&ctx[qg * 1024 + h * 64 + fd * 16 + g * 4] = pk;
  }
}

extern "C" void kernel_launch(void* const* d_in, const int* in_sizes, int n_in,
                              void* d_out, int out_size, void* d_ws, size_t ws_size,
                              hipStream_t stream) {
  const float* query = (const float*)d_in[0];
  const float* key = (const float*)d_in[1];
  const float* value = (const float*)d_in[2];
  const int* mask = (const int*)d_in[3];
  const float* Wq = (const float*)d_in[4];
  const float* bq = (const float*)d_in[5];
  const float* Wk = (const float*)d_in[6];
  const float* bk = (const float*)d_in[7];
  const float* Wv = (const float*)d_in[8];
  const float* bv = (const float*)d_in[9];
  const float* Wo = (const float*)d_in[10];
  const float* bo = (const float*)d_in[11];
  float* out = (float*)d_out;

  const size_t MB = 1024 * 1024;
  if (ws_size < 40 * MB) return;  // need 40MB scratch
  char* ws = (char*)d_ws;
  unsigned short* WqT = (unsigned short*)(ws);
  unsigned short* WkT = (unsigned short*)(ws + 2 * MB);
  unsigned short* WvT = (unsigned short*)(ws + 4 * MB);
  unsigned short* WoT = (unsigned short*)(ws + 6 * MB);
  unsigned short* Qb = (unsigned short*)(ws + 8 * MB);
  unsigned short* Kb = (unsigned short*)(ws + 16 * MB);
  unsigned short* Vt = (unsigned short*)(ws + 24 * MB);
  unsigned short* ctx = (unsigned short*)(ws + 32 * MB);

  const dim3 tb(256);
  wt_kernel<<<dim3(16, 16), tb, 0, stream>>>(Wq, WqT);
  wt_kernel<<<dim3(16, 16), tb, 0, stream>>>(Wk, WkT);
  wt_kernel<<<dim3(16, 16), tb, 0, stream>>>(Wv, WvT);
  wt_kernel<<<dim3(16, 16), tb, 0, stream>>>(Wo, WoT);

  // Q = (query@Wq + bq) * 0.125 ; K = key@Wk + bk ; V (transposed layout) = value@Wv + bv
  gemm_kernel<0, 0><<<dim3(16, 32), tb, 0, stream>>>(query, WqT, bq, Qb, 4096, 1024, 1024, 0.125f);
  gemm_kernel<0, 0><<<dim3(16, 32), tb, 0, stream>>>(key, WkT, bk, Kb, 4096, 1024, 1024, 1.0f);
  gemm_kernel<0, 1><<<dim3(16, 32), tb, 0, stream>>>(value, WvT, bv, Vt, 4096, 1024, 1024, 1.0f);

  attn_kernel<<<dim3(32, 32), tb, 0, stream>>>(Qb, Kb, Vt, mask, ctx);

  // out = ctx@Wo + bo  (fp32 out)
  gemm_kernel<1, 2><<<dim3(16, 32), tb, 0, stream>>>(ctx, WoT, bo, out, 4096, 1024, 1024, 1.0f);
}

// Round 2
// 224.604 us; speedup vs baseline: 1.0923x; 1.0923x over previous
//
#include <hip/hip_runtime.h>
#include <hip/hip_bf16.h>
#include <stdint.h>

typedef short s16x8 __attribute__((ext_vector_type(8)));
typedef float f32x4 __attribute__((ext_vector_type(4)));

union FragU { uint4 u; s16x8 v; };

static __device__ __forceinline__ uint32_t pk2bf(float a, float b) {
  union { __hip_bfloat162 h; uint32_t u; } cv;
  cv.h = __float22bfloat162_rn(make_float2(a, b));
  return cv.u;
}

static __device__ __forceinline__ unsigned short f2bf(float f) {
  union { float f; uint32_t u; } x; x.f = f;
  uint32_t r = x.u + 0x7FFFu + ((x.u >> 16) & 1u);  // RNE
  return (unsigned short)(r >> 16);
}

// ---------------- weight transpose: fp32 W[k][n] -> bf16 WT[n][k] ----------------
__global__ __launch_bounds__(256) void wt_kernel(const float* __restrict__ W,
                                                 unsigned short* __restrict__ WT) {
  __shared__ unsigned short tile[64][68];
  const int t = threadIdx.x;
  const int n0 = blockIdx.x * 64, k0 = blockIdx.y * 64;
  const int r = t >> 4, c4 = (t & 15) * 4;
#pragma unroll
  for (int i = 0; i < 4; ++i) {
    const int k = i * 16 + r;
    const float4 v = *(const float4*)&W[(k0 + k) * 1024 + n0 + c4];
    tile[k][c4 + 0] = f2bf(v.x);
    tile[k][c4 + 1] = f2bf(v.y);
    tile[k][c4 + 2] = f2bf(v.z);
    tile[k][c4 + 3] = f2bf(v.w);
  }
  __syncthreads();
#pragma unroll
  for (int i = 0; i < 4; ++i) {
    const int n = i * 16 + r;
    ushort4 o;
    o.x = tile[c4 + 0][n];
    o.y = tile[c4 + 1][n];
    o.z = tile[c4 + 2][n];
    o.w = tile[c4 + 3][n];
    *(ushort4*)&WT[(n0 + n) * 1024 + k0 + c4] = o;
  }
}

// ---------------- GEMM: C[M][N] = A[M][K] * BT[N][K]^T, epilogue (acc+bias)*scale
// AMODE: 0 = A fp32, 1 = A bf16.  OMODE: 0 = bf16 [M][N], 1 = bf16 Vt layout, 2 = fp32 [M][N]
// BM=128, BN=64, BK=32. 4 waves. Double-buffered LDS, one barrier per K-step.
template <int AMODE, int OMODE>
__global__ __launch_bounds__(256, 4) void gemm_kernel(const void* __restrict__ Aptr,
                                                      const unsigned short* __restrict__ BT,
                                                      const float* __restrict__ bias,
                                                      void* __restrict__ Out,
                                                      const int M, const int N, const int K,
                                                      const float scale) {
  constexpr int P = 40;
  __shared__ unsigned short As[2][128 * P];
  __shared__ unsigned short Bs[2][64 * P];
  const int t = threadIdx.x;
  const int lane = t & 63, w = t >> 6;
  const int g = lane >> 4, li = lane & 15;
  const int m0 = blockIdx.y * 128, n0 = blockIdx.x * 64;
  const int arow = t >> 1, acol = (t & 1) * 16;  // A: 16 shorts / thread
  const int brow = t >> 2, bcol = (t & 3) * 8;   // B: 8 shorts / thread

  uint4 ar0, ar1, br;
  auto loadT = [&](int k0) {
    if constexpr (AMODE == 0) {
      const float* ga = (const float*)Aptr + (size_t)(m0 + arow) * K + k0 + acol;
      const float4 f0 = *(const float4*)(ga + 0);
      const float4 f1 = *(const float4*)(ga + 4);
      const float4 f2 = *(const float4*)(ga + 8);
      const float4 f3 = *(const float4*)(ga + 12);
      ar0 = uint4{pk2bf(f0.x, f0.y), pk2bf(f0.z, f0.w), pk2bf(f1.x, f1.y), pk2bf(f1.z, f1.w)};
      ar1 = uint4{pk2bf(f2.x, f2.y), pk2bf(f2.z, f2.w), pk2bf(f3.x, f3.y), pk2bf(f3.z, f3.w)};
    } else {
      const unsigned short* ga = (const unsigned short*)Aptr + (size_t)(m0 + arow) * K + k0 + acol;
      ar0 = *(const uint4*)ga;
      ar1 = *(const uint4*)(ga + 8);
    }
    br = *(const uint4*)(BT + (size_t)(n0 + brow) * K + k0 + bcol);
  };
  auto storeT = [&](int buf) {
    *(uint4*)&As[buf][arow * P + acol] = ar0;
    *(uint4*)&As[buf][arow * P + acol + 8] = ar1;
    *(uint4*)&Bs[buf][brow * P + bcol] = br;
  };

  f32x4 acc[2][4] = {};
  loadT(0);
  storeT(0);
  __syncthreads();
  int cur = 0;
  for (int k0 = 0; k0 < K; k0 += 32) {
    const bool more = (k0 + 32) < K;
    if (more) loadT(k0 + 32);
    FragU a0, a1, bfr[4];
    a0.u = *(const uint4*)&As[cur][(w * 32 + li) * P + g * 8];
    a1.u = *(const uint4*)&As[cur][(w * 32 + 16 + li) * P + g * 8];
#pragma unroll
    for (int fn = 0; fn < 4; ++fn)
      bfr[fn].u = *(const uint4*)&Bs[cur][(fn * 16 + li) * P + g * 8];
#pragma unroll
    for (int fn = 0; fn < 4; ++fn) {
      acc[0][fn] = __builtin_amdgcn_mfma_f32_16x16x32_bf16(a0.v, bfr[fn].v, acc[0][fn], 0, 0, 0);
      acc[1][fn] = __builtin_amdgcn_mfma_f32_16x16x32_bf16(a1.v, bfr[fn].v, acc[1][fn], 0, 0, 0);
    }
    if (more) storeT(cur ^ 1);
    __syncthreads();
    cur ^= 1;
  }

#pragma unroll
  for (int fn = 0; fn < 4; ++fn) {
    const int n = n0 + fn * 16 + li;
    const float bv = bias[n];
#pragma unroll
    for (int fm = 0; fm < 2; ++fm) {
      const int mb = m0 + w * 32 + fm * 16 + g * 4;
      const f32x4 v = acc[fm][fn];
      if constexpr (OMODE == 0) {
        unsigned short* o = (unsigned short*)Out;
#pragma unroll
        for (int r = 0; r < 4; ++r) o[(size_t)(mb + r) * N + n] = f2bf((v[r] + bv) * scale);
      } else if constexpr (OMODE == 1) {
        unsigned short* o = (unsigned short*)Out;
        const int bb = mb >> 11, s = mb & 2047;
        ushort4 pk;
        pk.x = f2bf((v[0] + bv) * scale);
        pk.y = f2bf((v[1] + bv) * scale);
        pk.z = f2bf((v[2] + bv) * scale);
        pk.w = f2bf((v[3] + bv) * scale);
        *(ushort4*)&o[(size_t)(bb * 1024 + n) * 2048 + s] = pk;
      } else {
        float* o = (float*)Out;
#pragma unroll
        for (int r = 0; r < 4; ++r) o[(size_t)(mb + r) * N + n] = (v[r] + bv) * scale;
      }
    }
  }
}

// ---------------- flash attention ----------------
// Q bf16 [B*S][1024] pre-scaled by log2e/8; K bf16 [B*S][1024]; Vt bf16 [(b*1024+h*64+d)][2048]
// grid (S/64, B*H), 4 waves. Swapped QK^T (S^T = mfma(K,Q)); softmax in log2 domain;
// defer-max; per-lane partial l; P->B-frag via shfl (no LDS round trip); dbuf K/V staging.
__global__ __launch_bounds__(256, 3) void attn_kernel(const unsigned short* __restrict__ Qb,
                                                      const unsigned short* __restrict__ Kb,
                                                      const unsigned short* __restrict__ Vt,
                                                      const int* __restrict__ mask,
                                                      unsigned short* __restrict__ ctx) {
  constexpr int AP = 72;  // 144B pitch: 16B-aligned rows, 2-way banks
  __shared__ unsigned short Qs[64 * AP];
  __shared__ unsigned short Ks[2][64 * AP];
  __shared__ unsigned short Vs[2][64 * AP];
  __shared__ int flagS[2];
  const int t = threadIdx.x, lane = t & 63, w = t >> 6;
  const int g = lane >> 4, li = lane & 15;
  const int bh = blockIdx.y, b = bh >> 4, h = bh & 15;
  const int q0 = blockIdx.x * 64;
  const int row = t >> 2, cb = (t & 3) * 16;  // staging: 4 threads/row, 16 shorts each

  // stage Q once
  {
    const unsigned short* src = Qb + (size_t)(b * 2048 + q0 + row) * 1024 + h * 64 + cb;
    *(uint4*)&Qs[row * AP + cb] = *(const uint4*)src;
    *(uint4*)&Qs[row * AP + cb + 8] = *(const uint4*)(src + 8);
  }

  uint4 kr0, kr1, vr0, vr1;
  int mreg = 1;
  auto loadKV = [&](int kvn) {
    const unsigned short* ks = Kb + (size_t)(b * 2048 + kvn + row) * 1024 + h * 64 + cb;
    kr0 = *(const uint4*)ks;
    kr1 = *(const uint4*)(ks + 8);
    const unsigned short* vs = Vt + (size_t)(b * 1024 + h * 64 + row) * 2048 + kvn + cb;
    vr0 = *(const uint4*)vs;
    vr1 = *(const uint4*)(vs + 8);
    if (w == 0) mreg = mask[b * 2048 + kvn + lane];
  };
  auto storeKV = [&](int buf) {
    *(uint4*)&Ks[buf][row * AP + cb] = kr0;
    *(uint4*)&Ks[buf][row * AP + cb + 8] = kr1;
    *(uint4*)&Vs[buf][row * AP + cb] = vr0;
    *(uint4*)&Vs[buf][row * AP + cb + 8] = vr1;
    if (w == 0) {
      const unsigned long long bal = __ballot(mreg != 0);
      if (lane == 0) flagS[buf] = (bal == ~0ull);
    }
  };

  loadKV(0);
  storeKV(0);
  __syncthreads();

  // Q fragments are loop-invariant
  FragU qf[2];
  qf[0].u = *(const uint4*)&Qs[(w * 16 + li) * AP + 0 * 32 + g * 8];
  qf[1].u = *(const uint4*)&Qs[(w * 16 + li) * AP + 1 * 32 + g * 8];

  f32x4 acc_o[4] = {};
  float m_run = -1e30f, l_run = 0.f;
  int cur = 0;

  for (int tile = 0; tile < 32; ++tile) {
    const int kv0 = tile * 64;
    const bool more = tile + 1 < 32;
    if (more) loadKV(kv0 + 64);

    const bool allv = (flagS[cur] != 0);

    // QK^T (swapped): sc[fs] holds S^T[k = fs*16+g*4+r][q = w*16+li] (log2 domain)
    f32x4 sc[4] = {};
#pragma unroll
    for (int kc = 0; kc < 2; ++kc)
#pragma unroll
      for (int fs = 0; fs < 4; ++fs) {
        FragU kf;
        kf.u = *(const uint4*)&Ks[cur][(fs * 16 + li) * AP + kc * 32 + g * 8];
        sc[fs] = __builtin_amdgcn_mfma_f32_16x16x32_bf16(kf.v, qf[kc].v, sc[fs], 0, 0, 0);
      }

    float p[16];
#pragma unroll
    for (int fs = 0; fs < 4; ++fs) {
      if (allv) {
#pragma unroll
        for (int r = 0; r < 4; ++r) p[fs * 4 + r] = sc[fs][r];
      } else {
        const int4 mv = *(const int4*)&mask[b * 2048 + kv0 + fs * 16 + g * 4];
        p[fs * 4 + 0] = sc[fs][0] + (mv.x ? 0.f : -30000.f);
        p[fs * 4 + 1] = sc[fs][1] + (mv.y ? 0.f : -30000.f);
        p[fs * 4 + 2] = sc[fs][2] + (mv.z ? 0.f : -30000.f);
        p[fs * 4 + 3] = sc[fs][3] + (mv.w ? 0.f : -30000.f);
      }
    }
    // per-lane max (tree)
    float pm01 = fmaxf(fmaxf(p[0], p[1]), fmaxf(p[2], p[3]));
    float pm23 = fmaxf(fmaxf(p[4], p[5]), fmaxf(p[6], p[7]));
    float pm45 = fmaxf(fmaxf(p[8], p[9]), fmaxf(p[10], p[11]));
    float pm67 = fmaxf(fmaxf(p[12], p[13]), fmaxf(p[14], p[15]));
    const float pm = fmaxf(fmaxf(pm01, pm23), fmaxf(pm45, pm67));

    // defer-max: only rescale when the tile max grew past threshold
    if (!__all(pm <= m_run + 8.f)) {
      float gm = fmaxf(pm, __shfl_xor(pm, 16, 64));
      gm = fmaxf(gm, __shfl_xor(gm, 32, 64));
      const float m_new = fmaxf(m_run, gm);
      const float rescale = exp2f(m_run - m_new);
      m_run = m_new;
      l_run *= rescale;
#pragma unroll
      for (int fd = 0; fd < 4; ++fd) acc_o[fd] *= rescale;
    }

    float rs = 0.f;
#pragma unroll
    for (int i = 0; i < 16; ++i) {
      p[i] = exp2f(p[i] - m_run);
      rs += p[i];
    }
    l_run += rs;  // per-lane partial; reduced after the loop

    // pack P to bf16 pairs: pkk[fs][h2] = {p[4fs+2h2], p[4fs+2h2+1]}
    int pkk[4][2];
#pragma unroll
    for (int fs = 0; fs < 4; ++fs) {
      pkk[fs][0] = (int)pk2bf(p[fs * 4 + 0], p[fs * 4 + 1]);
      pkk[fs][1] = (int)pk2bf(p[fs * 4 + 2], p[fs * 4 + 3]);
    }

    // redistribute to B-frag via shfl and do PV
#pragma unroll
    for (int kc = 0; kc < 2; ++kc) {
      FragU pf;
      uint32_t* pr = (uint32_t*)&pf;
#pragma unroll
      for (int jj = 0; jj < 4; ++jj) {
        const int src = (((2 * g + (jj >> 1)) & 3) << 4) | li;
        const int lo = __shfl(pkk[2 * kc + 0][jj & 1], src, 64);
        const int hi = __shfl(pkk[2 * kc + 1][jj & 1], src, 64);
        pr[jj] = (uint32_t)((g & 2) ? hi : lo);
      }
#pragma unroll
      for (int fd = 0; fd < 4; ++fd) {
        FragU vf;
        vf.u = *(const uint4*)&Vs[cur][(fd * 16 + li) * AP + kc * 32 + g * 8];
        acc_o[fd] = __builtin_amdgcn_mfma_f32_16x16x32_bf16(vf.v, pf.v, acc_o[fd], 0, 0, 0);
      }
    }

    if (more) storeKV(cur ^ 1);
    __syncthreads();
    cur ^= 1;
  }

  // reduce partial l across the 4 g-lanes of each q
  float l = l_run + __shfl_xor(l_run, 16, 64);
  l += __shfl_xor(l, 32, 64);
  const float inv_l = 1.0f / l;
  const int qg = b * 2048 + q0 + w * 16 + li;
#pragma unroll
  for (int fd = 0; fd < 4; ++fd) {
    ushort4 pk;
    pk.x = (unsigned short)(pk2bf(acc_o[fd][0] * inv_l, 0.f) & 0xFFFF);
    pk.y = (unsigned short)(pk2bf(acc_o[fd][1] * inv_l, 0.f) & 0xFFFF);
    pk.z = (unsigned short)(pk2bf(acc_o[fd][2] * inv_l, 0.f) & 0xFFFF);
    pk.w = (unsigned short)(pk2bf(acc_o[fd][3] * inv_l, 0.f) & 0xFFFF);
    *(ushort4*)&ctx[(size_t)qg * 1024 + h * 64 + fd * 16 + g * 4] = pk;
  }
}

extern "C" void kernel_launch(void* const* d_in, const int* in_sizes, int n_in,
                              void* d_out, int out_size, void* d_ws, size_t ws_size,
                              hipStream_t stream) {
  const float* query = (const float*)d_in[0];
  const float* key = (const float*)d_in[1];
  const float* value = (const float*)d_in[2];
  const int* mask = (const int*)d_in[3];
  const float* Wq = (const float*)d_in[4];
  const float* bq = (const float*)d_in[5];
  const float* Wk = (const float*)d_in[6];
  const float* bk = (const float*)d_in[7];
  const float* Wv = (const float*)d_in[8];
  const float* bv = (const float*)d_in[9];
  const float* Wo = (const float*)d_in[10];
  const float* bo = (const float*)d_in[11];
  float* out = (float*)d_out;

  const size_t MB = 1024 * 1024;
  if (ws_size < 40 * MB) return;
  char* ws = (char*)d_ws;
  unsigned short* WqT = (unsigned short*)(ws);
  unsigned short* WkT = (unsigned short*)(ws + 2 * MB);
  unsigned short* WvT = (unsigned short*)(ws + 4 * MB);
  unsigned short* WoT = (unsigned short*)(ws + 6 * MB);
  unsigned short* Qb = (unsigned short*)(ws + 8 * MB);
  unsigned short* Kb = (unsigned short*)(ws + 16 * MB);
  unsigned short* Vt = (unsigned short*)(ws + 24 * MB);
  unsigned short* ctx = (unsigned short*)(ws + 32 * MB);

  const dim3 tb(256);
  wt_kernel<<<dim3(16, 16), tb, 0, stream>>>(Wq, WqT);
  wt_kernel<<<dim3(16, 16), tb, 0, stream>>>(Wk, WkT);
  wt_kernel<<<dim3(16, 16), tb, 0, stream>>>(Wv, WvT);
  wt_kernel<<<dim3(16, 16), tb, 0, stream>>>(Wo, WoT);

  // Q = (query@Wq + bq) * (log2e/8)  -> softmax uses exp2 directly
  const float qscale = 0.125f * 1.4426950408889634f;
  gemm_kernel<0, 0><<<dim3(16, 32), tb, 0, stream>>>(query, WqT, bq, Qb, 4096, 1024, 1024, qscale);
  gemm_kernel<0, 0><<<dim3(16, 32), tb, 0, stream>>>(key, WkT, bk, Kb, 4096, 1024, 1024, 1.0f);
  gemm_kernel<0, 1><<<dim3(16, 32), tb, 0, stream>>>(value, WvT, bv, Vt, 4096, 1024, 1024, 1.0f);

  attn_kernel<<<dim3(32, 32), tb, 0, stream>>>(Qb, Kb, Vt, mask, ctx);

  gemm_kernel<1, 2><<<dim3(16, 32), tb, 0, stream>>>(ctx, WoT, bo, out, 4096, 1024, 1024, 1.0f);
}

// Round 4
// 185.851 us; speedup vs baseline: 1.3201x; 1.2085x over previous
//
#include <hip/hip_runtime.h>
#include <hip/hip_bf16.h>
#include <stdint.h>

typedef short s16x8 __attribute__((ext_vector_type(8)));
typedef float f32x4 __attribute__((ext_vector_type(4)));
typedef float f32x16 __attribute__((ext_vector_type(16)));

union FragU { uint4 u; s16x8 v; };

static __device__ __forceinline__ uint32_t pk2bf(float a, float b) {
  union { __hip_bfloat162 h; uint32_t u; } cv;
  cv.h = __float22bfloat162_rn(make_float2(a, b));
  return cv.u;
}

static __device__ __forceinline__ unsigned short f2bf(float f) {
  union { float f; uint32_t u; } x; x.f = f;
  uint32_t r = x.u + 0x7FFFu + ((x.u >> 16) & 1u);  // RNE
  return (unsigned short)(r >> 16);
}

// ---------------- weight transpose: fp32 W[k][n] -> bf16 WT[n][k] ----------------
__global__ __launch_bounds__(256) void wt_kernel(const float* __restrict__ W,
                                                 unsigned short* __restrict__ WT) {
  __shared__ unsigned short tile[64][68];
  const int t = threadIdx.x;
  const int n0 = blockIdx.x * 64, k0 = blockIdx.y * 64;
  const int r = t >> 4, c4 = (t & 15) * 4;
#pragma unroll
  for (int i = 0; i < 4; ++i) {
    const int k = i * 16 + r;
    const float4 v = *(const float4*)&W[(k0 + k) * 1024 + n0 + c4];
    tile[k][c4 + 0] = f2bf(v.x);
    tile[k][c4 + 1] = f2bf(v.y);
    tile[k][c4 + 2] = f2bf(v.z);
    tile[k][c4 + 3] = f2bf(v.w);
  }
  __syncthreads();
#pragma unroll
  for (int i = 0; i < 4; ++i) {
    const int n = i * 16 + r;
    ushort4 o;
    o.x = tile[c4 + 0][n];
    o.y = tile[c4 + 1][n];
    o.z = tile[c4 + 2][n];
    o.w = tile[c4 + 3][n];
    *(ushort4*)&WT[(n0 + n) * 1024 + k0 + c4] = o;
  }
}

// ---------------- GEMM: C[M][N] = A[M][K] * BT[N][K]^T, epilogue (acc+bias)*scale
// AMODE: 0 = A fp32, 1 = A bf16.  OMODE: 0 = bf16 [M][N], 1 = bf16 Vt layout, 2 = fp32 [M][N]
// BM=128, BN=128, BK=32. 4 waves (2x2), each 64x64 (4x4 fragments). Dbuf, 1 barrier/step.
template <int AMODE, int OMODE>
__global__ __launch_bounds__(256, 2) void gemm_kernel(const void* __restrict__ Aptr,
                                                      const unsigned short* __restrict__ BT,
                                                      const float* __restrict__ bias,
                                                      void* __restrict__ Out,
                                                      const int M, const int N, const int K,
                                                      const float scale) {
  __shared__ unsigned short As[2][128 * 32];
  __shared__ unsigned short Bs[2][128 * 32];
  const int t = threadIdx.x;
  const int lane = t & 63, w = t >> 6;
  const int g = lane >> 4, li = lane & 15;
  const int wr = (w >> 1) * 64, wc = (w & 1) * 64;
  const int m0 = blockIdx.y * 128, n0 = blockIdx.x * 128;
  const int srow = t >> 2, sch = (t & 3) * 8;  // 128 rows x 32 shorts; 2 rows per thread

  uint4 ar0, ar1, br0, br1;
  auto loadT = [&](int k0) {
    if constexpr (AMODE == 0) {
      const float* ga = (const float*)Aptr + (size_t)(m0 + srow) * K + k0 + sch;
      const float4 f0 = *(const float4*)ga, f1 = *(const float4*)(ga + 4);
      ar0 = uint4{pk2bf(f0.x, f0.y), pk2bf(f0.z, f0.w), pk2bf(f1.x, f1.y), pk2bf(f1.z, f1.w)};
      const float* gb = (const float*)Aptr + (size_t)(m0 + 64 + srow) * K + k0 + sch;
      const float4 f2 = *(const float4*)gb, f3 = *(const float4*)(gb + 4);
      ar1 = uint4{pk2bf(f2.x, f2.y), pk2bf(f2.z, f2.w), pk2bf(f3.x, f3.y), pk2bf(f3.z, f3.w)};
    } else {
      ar0 = *(const uint4*)((const unsigned short*)Aptr + (size_t)(m0 + srow) * K + k0 + sch);
      ar1 = *(const uint4*)((const unsigned short*)Aptr + (size_t)(m0 + 64 + srow) * K + k0 + sch);
    }
    br0 = *(const uint4*)(BT + (size_t)(n0 + srow) * K + k0 + sch);
    br1 = *(const uint4*)(BT + (size_t)(n0 + 64 + srow) * K + k0 + sch);
  };
  auto storeT = [&](int buf) {
    *(uint4*)&As[buf][srow * 32 + sch] = ar0;
    *(uint4*)&As[buf][(64 + srow) * 32 + sch] = ar1;
    *(uint4*)&Bs[buf][srow * 32 + sch] = br0;
    *(uint4*)&Bs[buf][(64 + srow) * 32 + sch] = br1;
  };

  f32x4 acc[4][4] = {};
  loadT(0);
  storeT(0);
  __syncthreads();
  int cur = 0;
  for (int k0 = 0; k0 < K; k0 += 32) {
    const bool more = (k0 + 32) < K;
    if (more) loadT(k0 + 32);
    FragU a[4], bf[4];
#pragma unroll
    for (int i = 0; i < 4; ++i) {
      a[i].u = *(const uint4*)&As[cur][(wr + i * 16 + li) * 32 + g * 8];
      bf[i].u = *(const uint4*)&Bs[cur][(wc + i * 16 + li) * 32 + g * 8];
    }
#pragma unroll
    for (int fm = 0; fm < 4; ++fm)
#pragma unroll
      for (int fn = 0; fn < 4; ++fn)
        acc[fm][fn] = __builtin_amdgcn_mfma_f32_16x16x32_bf16(a[fm].v, bf[fn].v, acc[fm][fn], 0, 0, 0);
    if (more) storeT(cur ^ 1);
    __syncthreads();
    cur ^= 1;
  }

#pragma unroll
  for (int fn = 0; fn < 4; ++fn) {
    const int n = n0 + wc + fn * 16 + li;
    const float bv = bias[n];
#pragma unroll
    for (int fm = 0; fm < 4; ++fm) {
      const int mb = m0 + wr + fm * 16 + g * 4;
      const f32x4 v = acc[fm][fn];
      if constexpr (OMODE == 0) {
        unsigned short* o = (unsigned short*)Out;
#pragma unroll
        for (int r = 0; r < 4; ++r) o[(size_t)(mb + r) * N + n] = f2bf((v[r] + bv) * scale);
      } else if constexpr (OMODE == 1) {
        unsigned short* o = (unsigned short*)Out;
        const int bb = mb >> 11, s = mb & 2047;
        ushort4 pk;
        pk.x = f2bf((v[0] + bv) * scale);
        pk.y = f2bf((v[1] + bv) * scale);
        pk.z = f2bf((v[2] + bv) * scale);
        pk.w = f2bf((v[3] + bv) * scale);
        *(ushort4*)&o[(size_t)(bb * 1024 + n) * 2048 + s] = pk;
      } else {
        float* o = (float*)Out;
#pragma unroll
        for (int r = 0; r < 4; ++r) o[(size_t)(mb + r) * N + n] = (v[r] + bv) * scale;
      }
    }
  }
}

// ---------------- flash attention, 32x32 swapped structure ----------------
// Q bf16 [B*S][1024] pre-scaled by log2e/8; K bf16 [B*S][1024]; Vt bf16 [(b*1024+h*64+d)][2048]
// grid (S/128, B*H), 4 waves; wave owns 32 q-rows (q = lane&31), KV tile = 64.
// S^T = mfma_32x32x16(K, Q) -> half P-row lane-local; softmax in-register (log2 domain);
// P -> PV B-frag via 16 cvt_pk + 8 v_permlane32_swap; O^T = mfma(V^T, P) keeps q lane-local.
// R4 fix: scalar pair-reductions (pm, l) via __shfl_xor — the inline-asm permlane swap with
// identical tied operands could collapse to one register (undefined swap).
__global__ __launch_bounds__(256, 2) void attn_kernel(const unsigned short* __restrict__ Qb,
                                                      const unsigned short* __restrict__ Kb,
                                                      const unsigned short* __restrict__ Vt,
                                                      const int* __restrict__ mask,
                                                      unsigned short* __restrict__ ctx) {
  __shared__ unsigned short Ks[2][64 * 64];  // [kv][d], byte ^= (kv&7)<<4
  __shared__ unsigned short Vs[2][64 * 64];  // [d][kv], byte ^= (d&7)<<4
  const int t = threadIdx.x, lane = t & 63, w = t >> 6;
  const int l31 = lane & 31, hi = lane >> 5;
  const int b = blockIdx.y >> 4, h = blockIdx.y & 15;
  const int q0 = blockIdx.x * 128;
  const int qrow = b * 2048 + q0 + w * 32 + l31;

  const int srow = t >> 3, sch = t & 7;  // staging: row = t>>3 (0..31), ch = t&7

  uint4 kr0, kr1, vr0, vr1;
  int mv = 1;
  auto loadKV = [&](int kvn) {
    const unsigned short* kbase = Kb + (size_t)(b * 2048 + kvn) * 1024 + h * 64;
    kr0 = *(const uint4*)(kbase + (size_t)srow * 1024 + sch * 8);
    kr1 = *(const uint4*)(kbase + (size_t)(srow + 32) * 1024 + sch * 8);
    const unsigned short* vbase = Vt + (size_t)(b * 1024 + h * 64) * 2048 + kvn;
    vr0 = *(const uint4*)(vbase + (size_t)srow * 2048 + sch * 8);
    vr1 = *(const uint4*)(vbase + (size_t)(srow + 32) * 2048 + sch * 8);
    mv = mask[b * 2048 + kvn + lane];
  };
  auto storeKV = [&](int buf) {
    char* kb = (char*)&Ks[buf][0];
    char* vb = (char*)&Vs[buf][0];
    const int o0 = srow * 128 + ((sch * 16) ^ ((srow & 7) << 4));
    const int o1 = (srow + 32) * 128 + ((sch * 16) ^ ((srow & 7) << 4));
    *(uint4*)(kb + o0) = kr0;
    *(uint4*)(kb + o1) = kr1;
    *(uint4*)(vb + o0) = vr0;
    *(uint4*)(vb + o1) = vr1;
  };

  // loop-invariant Q fragments (B-operand of QK): qf[dc] = Q[qrow][h*64 + dc*16 + hi*8 ..+7]
  FragU qf[4];
  {
    const unsigned short* qb = Qb + (size_t)qrow * 1024 + h * 64 + hi * 8;
#pragma unroll
    for (int dc = 0; dc < 4; ++dc) qf[dc].u = *(const uint4*)(qb + dc * 16);
  }

  loadKV(0);
  storeKV(0);
  __syncthreads();

  f32x16 acc[2] = {};  // O^T[d = dt*32 + rowmap][q = l31]
  float m_run = -1e30f, l_run = 0.f;
  int cur = 0;

  for (int tile = 0; tile < 32; ++tile) {
    const bool more = tile + 1 < 32;
    const int mvcur = mv;
    if (more) loadKV((tile + 1) * 64);

    // QK^T: sc[t2][reg] = S^T[kv = t2*32 + (reg&3)+8*(reg>>2)+4*hi][q = l31]
    f32x16 sc[2] = {};
    {
      const char* kb = (const char*)&Ks[cur][0];
#pragma unroll
      for (int t2 = 0; t2 < 2; ++t2) {
        const int row = t2 * 32 + l31;
        const int sw = (row & 7) << 4;
        const int rb = row * 128;
#pragma unroll
        for (int dc = 0; dc < 4; ++dc) {
          FragU kf;
          kf.u = *(const uint4*)(kb + rb + ((16 * (dc * 2 + hi)) ^ sw));
          sc[t2] = __builtin_amdgcn_mfma_f32_32x32x16_bf16(kf.v, qf[dc].v, sc[t2], 0, 0, 0);
        }
      }
    }

    const bool allv = __all(mvcur != 0);
    if (!allv) {
#pragma unroll
      for (int t2 = 0; t2 < 2; ++t2)
#pragma unroll
        for (int r = 0; r < 16; ++r) {
          const int kvv = t2 * 32 + (r & 3) + 8 * (r >> 2) + 4 * hi;
          sc[t2][r] += (__shfl(mvcur, kvv, 64) ? 0.f : -30000.f);
        }
    }

    // in-register max over 32 values + pair max across hi halves (shfl_xor: safe)
    float pm = sc[0][0];
#pragma unroll
    for (int t2 = 0; t2 < 2; ++t2)
#pragma unroll
      for (int r = 0; r < 16; ++r) pm = fmaxf(pm, sc[t2][r]);
    pm = fmaxf(pm, __shfl_xor(pm, 32, 64));

    // defer-max (log2 domain, THR=8)
    if (!__all(pm <= m_run + 8.f)) {
      const float m_new = fmaxf(m_run, pm);
      const float rsc = __builtin_amdgcn_exp2f(m_run - m_new);
      m_run = m_new;
      l_run *= rsc;
#pragma unroll
      for (int dt = 0; dt < 2; ++dt)
#pragma unroll
        for (int r = 0; r < 16; ++r) acc[dt][r] *= rsc;
    }

    // exp2 + partial row-sum (per-lane; pair-reduced at end)
    float rs = 0.f;
#pragma unroll
    for (int t2 = 0; t2 < 2; ++t2)
#pragma unroll
      for (int r = 0; r < 16; ++r) {
        const float e = __builtin_amdgcn_exp2f(sc[t2][r] - m_run);
        sc[t2][r] = e;
        rs += e;
      }
    l_run += rs;

    // P -> B-frag (B[kv][q]): 16 cvt_pk + 8 permlane32_swap (distinct operands: safe)
    FragU pf[4];
#pragma unroll
    for (int ks = 0; ks < 4; ++ks) {
      const int t2 = ks >> 1, s8 = (ks & 1) * 8;
      uint32_t U = pk2bf(sc[t2][s8 + 0], sc[t2][s8 + 1]);
      uint32_t V2 = pk2bf(sc[t2][s8 + 2], sc[t2][s8 + 3]);
      uint32_t X = pk2bf(sc[t2][s8 + 4], sc[t2][s8 + 5]);
      uint32_t Y = pk2bf(sc[t2][s8 + 6], sc[t2][s8 + 7]);
      asm("v_permlane32_swap_b32 %0, %1" : "+v"(U), "+v"(X));
      asm("v_permlane32_swap_b32 %0, %1" : "+v"(V2), "+v"(Y));
      pf[ks].u = uint4{U, V2, X, Y};
    }

    // PV: O^T[d][q] += V^T[d][kv] * P^T[kv][q]
    {
      const char* vb = (const char*)&Vs[cur][0];
#pragma unroll
      for (int dt = 0; dt < 2; ++dt) {
        const int drow = dt * 32 + l31;
        const int sw = (drow & 7) << 4;
        const int rb = drow * 128;
#pragma unroll
        for (int ks = 0; ks < 4; ++ks) {
          FragU vf;
          vf.u = *(const uint4*)(vb + rb + ((16 * (ks * 2 + hi)) ^ sw));
          acc[dt] = __builtin_amdgcn_mfma_f32_32x32x16_bf16(vf.v, pf[ks].v, acc[dt], 0, 0, 0);
        }
      }
    }

    if (more) storeKV(cur ^ 1);
    __syncthreads();
    cur ^= 1;
  }

  // pair-reduce l across hi halves (shfl_xor: safe), normalize, store O
  const float l_tot = l_run + __shfl_xor(l_run, 32, 64);
  const float inv_l = 1.0f / l_tot;
  unsigned short* cb = ctx + (size_t)qrow * 1024 + h * 64;
#pragma unroll
  for (int dt = 0; dt < 2; ++dt)
#pragma unroll
    for (int rq = 0; rq < 4; ++rq) {
      uint2 o;
      o.x = pk2bf(acc[dt][rq * 4 + 0] * inv_l, acc[dt][rq * 4 + 1] * inv_l);
      o.y = pk2bf(acc[dt][rq * 4 + 2] * inv_l, acc[dt][rq * 4 + 3] * inv_l);
      *(uint2*)(cb + dt * 32 + rq * 8 + hi * 4) = o;
    }
}

extern "C" void kernel_launch(void* const* d_in, const int* in_sizes, int n_in,
                              void* d_out, int out_size, void* d_ws, size_t ws_size,
                              hipStream_t stream) {
  const float* query = (const float*)d_in[0];
  const float* key = (const float*)d_in[1];
  const float* value = (const float*)d_in[2];
  const int* mask = (const int*)d_in[3];
  const float* Wq = (const float*)d_in[4];
  const float* bq = (const float*)d_in[5];
  const float* Wk = (const float*)d_in[6];
  const float* bk = (const float*)d_in[7];
  const float* Wv = (const float*)d_in[8];
  const float* bv = (const float*)d_in[9];
  const float* Wo = (const float*)d_in[10];
  const float* bo = (const float*)d_in[11];
  float* out = (float*)d_out;

  const size_t MB = 1024 * 1024;
  if (ws_size < 40 * MB) return;
  char* ws = (char*)d_ws;
  unsigned short* WqT = (unsigned short*)(ws);
  unsigned short* WkT = (unsigned short*)(ws + 2 * MB);
  unsigned short* WvT = (unsigned short*)(ws + 4 * MB);
  unsigned short* WoT = (unsigned short*)(ws + 6 * MB);
  unsigned short* Qb = (unsigned short*)(ws + 8 * MB);
  unsigned short* Kb = (unsigned short*)(ws + 16 * MB);
  unsigned short* Vt = (unsigned short*)(ws + 24 * MB);
  unsigned short* ctx = (unsigned short*)(ws + 32 * MB);

  const dim3 tb(256);
  wt_kernel<<<dim3(16, 16), tb, 0, stream>>>(Wq, WqT);
  wt_kernel<<<dim3(16, 16), tb, 0, stream>>>(Wk, WkT);
  wt_kernel<<<dim3(16, 16), tb, 0, stream>>>(Wv, WvT);
  wt_kernel<<<dim3(16, 16), tb, 0, stream>>>(Wo, WoT);

  // Q = (query@Wq + bq) * (log2e/8)  -> softmax uses exp2 directly
  const float qscale = 0.125f * 1.4426950408889634f;
  gemm_kernel<0, 0><<<dim3(8, 32), tb, 0, stream>>>(query, WqT, bq, Qb, 4096, 1024, 1024, qscale);
  gemm_kernel<0, 0><<<dim3(8, 32), tb, 0, stream>>>(key, WkT, bk, Kb, 4096, 1024, 1024, 1.0f);
  gemm_kernel<0, 1><<<dim3(8, 32), tb, 0, stream>>>(value, WvT, bv, Vt, 4096, 1024, 1024, 1.0f);

  attn_kernel<<<dim3(16, 32), tb, 0, stream>>>(Qb, Kb, Vt, mask, ctx);

  gemm_kernel<1, 2><<<dim3(8, 32), tb, 0, stream>>>(ctx, WoT, bo, out, 4096, 1024, 1024, 1.0f);
}